// Round 2
// 256.074 us; speedup vs baseline: 1.0418x; 1.0418x over previous
//
#include <hip/hip_runtime.h>
#include <hip/hip_bf16.h>
#include <stdint.h>

typedef unsigned short u16;
typedef __attribute__((ext_vector_type(4))) float f32x4;
typedef __attribute__((ext_vector_type(8))) __bf16 bf16x8;
typedef __attribute__((ext_vector_type(8))) unsigned short u16x8;
typedef __attribute__((ext_vector_type(4))) unsigned short u16x4;

#define SEQ 2048
#define HID 2048
#define HD  128

__device__ __forceinline__ float b2f(u16 v) {
    union { float f; unsigned u; } c; c.u = ((unsigned)v) << 16; return c.f;
}
__device__ __forceinline__ u16 f2b(float f) {
    union { float f; unsigned u; } c; c.f = f;
    unsigned r = c.u + 0x7fffu + ((c.u >> 16) & 1u);
    return (u16)(r >> 16);
}
__device__ __forceinline__ bf16x8 tob(u16x8 v) {
    union { u16x8 u; bf16x8 b; } c; c.u = v; return c.b;
}
__device__ __forceinline__ u16x8 ld8(const u16* p) { return *(const u16x8*)p; }

typedef const __attribute__((address_space(1))) unsigned int* gas_ptr;
typedef __attribute__((address_space(3))) unsigned int* las_ptr;
__device__ __forceinline__ void gld16(const void* g, void* l) {
    __builtin_amdgcn_global_load_lds((gas_ptr)g, (las_ptr)l, 16, 0, 0);
}

// ---------------- f32 -> bf16 weight conversion ----------------
__global__ __launch_bounds__(256) void k_conv(const float* __restrict__ src,
                                              u16* __restrict__ dst) {
    const size_t i = ((size_t)blockIdx.x * 256 + threadIdx.x) * 8;
    f32x4 a = *(const f32x4*)(src + i);
    f32x4 b = *(const f32x4*)(src + i + 4);
    u16x8 o;
#pragma unroll
    for (int e = 0; e < 4; ++e) { o[e] = f2b(a[e]); o[e + 4] = f2b(b[e]); }
    *(u16x8*)(dst + i) = o;
}

// ---------------- RMSNorm over HIDDEN (f32 in, bf16 out) ----------------
__global__ __launch_bounds__(256) void k_rmsnorm(const float* __restrict__ x,
                                                 const float* __restrict__ w,
                                                 u16* __restrict__ o) {
    const int row = blockIdx.x, t = threadIdx.x;
    const float* xr = x + (size_t)row * HID + t * 8;
    f32x4 xa = *(const f32x4*)xr;
    f32x4 xb = *(const f32x4*)(xr + 4);
    float xf[8]; float ss = 0.f;
#pragma unroll
    for (int e = 0; e < 4; ++e) { xf[e] = xa[e]; xf[e + 4] = xb[e]; }
#pragma unroll
    for (int e = 0; e < 8; ++e) ss += xf[e] * xf[e];
#pragma unroll
    for (int m = 32; m; m >>= 1) ss += __shfl_xor(ss, m);
    __shared__ float red[4];
    if ((t & 63) == 0) red[t >> 6] = ss;
    __syncthreads();
    ss = red[0] + red[1] + red[2] + red[3];
    const float sc = rsqrtf(ss * (1.0f / HID) + 1e-6f);
    f32x4 wa = *(const f32x4*)(w + t * 8);
    f32x4 wb = *(const f32x4*)(w + t * 8 + 4);
    u16x8 ov;
#pragma unroll
    for (int e = 0; e < 4; ++e) {
        ov[e] = f2b(xf[e] * sc * wa[e]);
        ov[e + 4] = f2b(xf[e + 4] * sc * wb[e]);
    }
    *(u16x8*)(o + (size_t)row * HID + t * 8) = ov;
}

// Staging: 8 gld16 per wave per tile. LDS dest is linear (wave*1024 + lane*16);
// the chunk permutation lives on the GLOBAL source address (rule #21: linear
// dest + inverse-swizzled source + swizzled read).
// LDS(row, c) holds global chunk c ^ ((row>>1)&3); read chunk q at
// LDS chunk q ^ ((row>>1)&3). Read bank check: per 16-lane phase, banks
// (l16&1)*16 + (q^((l16>>1)&3))*4 -> all 8 four-bank groups x2 lanes = min.
#define STAGE_G(buf, k0)                                                      \
    do {                                                                      \
        char* a0 = (char*)&As[buf][0][0] + wave * 1024;                       \
        char* a1 = (char*)&As[buf][1][0] + wave * 1024;                       \
        char* b0 = (char*)&Bs[buf][0][0] + wave * 1024;                       \
        char* b1 = (char*)&Bs[buf][1][0] + wave * 1024;                       \
        gld16(ga + (k0), a0);                                                 \
        gld16(ga + (k0) + rowskip, a0 + 4096);                                \
        gld16(ga + (k0) + 32, a1);                                            \
        gld16(ga + (k0) + 32 + rowskip, a1 + 4096);                           \
        gld16(gb + (k0), b0);                                                 \
        gld16(gb + (k0) + rowskip, b0 + 4096);                                \
        gld16(gb + (k0) + 32, b1);                                            \
        gld16(gb + (k0) + 32 + rowskip, b1 + 4096);                           \
    } while (0)

// ------- QKV GEMM: dbuf LDS, counted vmcnt(8), swizzled reads, scatter epilogue -------
__global__ __launch_bounds__(256) void k_gemm_qkv(const u16* __restrict__ A,
                                                  const u16* __restrict__ B,
                                                  u16* __restrict__ qraw,
                                                  u16* __restrict__ kraw,
                                                  u16* __restrict__ vtr,
                                                  int K) {
    __shared__ u16 As[2][2][128 * 32];
    __shared__ u16 Bs[2][2][128 * 32];
    const int tid = threadIdx.x;
    const int wave = tid >> 6, lane = tid & 63, quad = lane >> 4, l16 = lane & 15;
    const int wm = wave >> 1, wn = wave & 1;
    const int sw = (l16 >> 1) & 3;
    const int m0 = blockIdx.x * 128, n0 = blockIdx.y * 128;
    f32x4 acc[4][4];
#pragma unroll
    for (int i = 0; i < 4; ++i)
#pragma unroll
        for (int j = 0; j < 4; ++j) acc[i][j] = (f32x4){0.f, 0.f, 0.f, 0.f};

    const int gchunk = (tid & 3) ^ ((tid >> 3) & 3);
    const u16* ga = A + (size_t)(m0 + (tid >> 2)) * K + gchunk * 8;
    const u16* gb = B + (size_t)(n0 + (tid >> 2)) * K + gchunk * 8;
    const size_t rowskip = (size_t)64 * K;

    STAGE_G(0, 0);
    const int nk = K >> 6;
    for (int t = 0; t < nk; ++t) {
        const int cur = t & 1;
        if (t + 1 < nk) {
            STAGE_G(cur ^ 1, (t + 1) * 64);
            asm volatile("s_waitcnt vmcnt(8)" ::: "memory");
        } else {
            asm volatile("s_waitcnt vmcnt(0)" ::: "memory");
        }
        __builtin_amdgcn_s_barrier();
        asm volatile("" ::: "memory");
#pragma unroll
        for (int h = 0; h < 2; ++h) {
            const u16* as = &As[cur][h][0];
            const u16* bs = &Bs[cur][h][0];
            bf16x8 af[4], bfr[4];
#pragma unroll
            for (int i = 0; i < 4; ++i)
                af[i] = tob(ld8(as + (wm * 64 + i * 16 + l16) * 32 + ((quad ^ sw) << 3)));
#pragma unroll
            for (int j = 0; j < 4; ++j)
                bfr[j] = tob(ld8(bs + (wn * 64 + j * 16 + l16) * 32 + ((quad ^ sw) << 3)));
#pragma unroll
            for (int i = 0; i < 4; ++i)
#pragma unroll
                for (int j = 0; j < 4; ++j)
                    acc[i][j] = __builtin_amdgcn_mfma_f32_16x16x32_bf16(af[i], bfr[j], acc[i][j], 0, 0, 0);
        }
        asm volatile("" ::: "memory");
        __builtin_amdgcn_s_barrier();
    }
#pragma unroll
    for (int i = 0; i < 4; ++i) {
        const int row = m0 + wm * 64 + i * 16 + quad * 4;
#pragma unroll
        for (int j = 0; j < 4; ++j) {
            const int col = n0 + wn * 64 + j * 16 + l16;
#pragma unroll
            for (int r = 0; r < 4; ++r) {
                const u16 val = f2b(acc[i][j][r]);
                const int s = row + r;
                if (col < 2048) {
                    const int head = col >> 7, d = col & 127;
                    qraw[((size_t)head * SEQ + s) * HD + d] = val;
                } else if (col < 3072) {
                    const int c = col - 2048, kv = c >> 7, d = c & 127;
                    kraw[((size_t)kv * SEQ + s) * HD + d] = val;
                } else {
                    const int c = col - 3072, kv = c >> 7, d = c & 127;
                    vtr[(size_t)kv * HD * SEQ + (size_t)d * SEQ + s] = val;
                }
            }
        }
    }
}

// ------- O-projection GEMM: same dbuf + counted vmcnt + swizzle, f32 epilogue -------
__global__ __launch_bounds__(256) void k_gemm_of(const u16* __restrict__ A,
                                                 const u16* __restrict__ B,
                                                 float* __restrict__ C,
                                                 int N, int K) {
    __shared__ u16 As[2][2][128 * 32];
    __shared__ u16 Bs[2][2][128 * 32];
    const int tid = threadIdx.x;
    const int wave = tid >> 6, lane = tid & 63, quad = lane >> 4, l16 = lane & 15;
    const int wm = wave >> 1, wn = wave & 1;
    const int sw = (l16 >> 1) & 3;
    const int m0 = blockIdx.x * 128, n0 = blockIdx.y * 128;
    f32x4 acc[4][4];
#pragma unroll
    for (int i = 0; i < 4; ++i)
#pragma unroll
        for (int j = 0; j < 4; ++j) acc[i][j] = (f32x4){0.f, 0.f, 0.f, 0.f};

    const int gchunk = (tid & 3) ^ ((tid >> 3) & 3);
    const u16* ga = A + (size_t)(m0 + (tid >> 2)) * K + gchunk * 8;
    const u16* gb = B + (size_t)(n0 + (tid >> 2)) * K + gchunk * 8;
    const size_t rowskip = (size_t)64 * K;

    STAGE_G(0, 0);
    const int nk = K >> 6;
    for (int t = 0; t < nk; ++t) {
        const int cur = t & 1;
        if (t + 1 < nk) {
            STAGE_G(cur ^ 1, (t + 1) * 64);
            asm volatile("s_waitcnt vmcnt(8)" ::: "memory");
        } else {
            asm volatile("s_waitcnt vmcnt(0)" ::: "memory");
        }
        __builtin_amdgcn_s_barrier();
        asm volatile("" ::: "memory");
#pragma unroll
        for (int h = 0; h < 2; ++h) {
            const u16* as = &As[cur][h][0];
            const u16* bs = &Bs[cur][h][0];
            bf16x8 af[4], bfr[4];
#pragma unroll
            for (int i = 0; i < 4; ++i)
                af[i] = tob(ld8(as + (wm * 64 + i * 16 + l16) * 32 + ((quad ^ sw) << 3)));
#pragma unroll
            for (int j = 0; j < 4; ++j)
                bfr[j] = tob(ld8(bs + (wn * 64 + j * 16 + l16) * 32 + ((quad ^ sw) << 3)));
#pragma unroll
            for (int i = 0; i < 4; ++i)
#pragma unroll
                for (int j = 0; j < 4; ++j)
                    acc[i][j] = __builtin_amdgcn_mfma_f32_16x16x32_bf16(af[i], bfr[j], acc[i][j], 0, 0, 0);
        }
        asm volatile("" ::: "memory");
        __builtin_amdgcn_s_barrier();
    }
#pragma unroll
    for (int i = 0; i < 4; ++i) {
        const int row = m0 + wm * 64 + i * 16 + quad * 4;
#pragma unroll
        for (int j = 0; j < 4; ++j) {
            const int col = n0 + wn * 64 + j * 16 + l16;
#pragma unroll
            for (int r = 0; r < 4; ++r)
                C[(size_t)(row + r) * N + col] = acc[i][j][r];
        }
    }
}

// ---------------- in-place RoPE + per-head RMSNorm ----------------
__global__ __launch_bounds__(256) void k_ropenorm(const int* __restrict__ pos,
                                                  const float* __restrict__ qw,
                                                  const float* __restrict__ kw,
                                                  u16* __restrict__ qraw,
                                                  u16* __restrict__ kraw) {
    const int s = blockIdx.x;
    const int h = blockIdx.y * 4 + (threadIdx.x >> 6);
    const int d = threadIdx.x & 63;
    const bool isq = h < 16;
    u16* row = isq ? (qraw + ((size_t)h * SEQ + s) * HD)
                   : (kraw + ((size_t)(h - 16) * SEQ + s) * HD);
    const float x1 = b2f(row[d]), x2 = b2f(row[d + 64]);
    const float p = (float)pos[s];
    const float inv = exp2f(-(float)d * (2.0f / 128.0f) * 13.287712379549449f);
    const float fr = p * inv;
    const float c = cosf(fr), sn = sinf(fr);
    const float o1 = x1 * c - x2 * sn;
    const float o2 = x2 * c + x1 * sn;
    float ss = o1 * o1 + o2 * o2;
#pragma unroll
    for (int m = 32; m; m >>= 1) ss += __shfl_xor(ss, m);
    const float sc = rsqrtf(ss * (1.0f / HD) + 1e-6f);
    const float* w = isq ? qw : kw;
    row[d] = f2b(o1 * sc * w[d]);
    row[d + 64] = f2b(o2 * sc * w[d + 64]);
}

// ---------------- causal flash attention ----------------
// Balanced qt remap, M=0 softmax, dbuf K/V, S^T operand order, 1 barrier/iter.
__global__ __launch_bounds__(256) void k_attn(const u16* __restrict__ qh,
                                              const u16* __restrict__ kh,
                                              const u16* __restrict__ vt,
                                              u16* __restrict__ out) {
    const int tid = threadIdx.x;
    const int wave = tid >> 6, lane = tid & 63, quad = lane >> 4, l16 = lane & 15;
    const int head = blockIdx.y;
    const int bx = blockIdx.x;
    const int f = (bx & 1) ? 31 - (bx >> 1) : (bx >> 1);
    const int qt = (head < 8) ? f : 31 - f;
    const int kvh = head >> 1;
    const int q0 = qt * 64;

    __shared__ u16 Ks[2][64 * 128];
    __shared__ u16 Vts[2][128 * 64];
    __shared__ u16 Ps[4][16 * 64];

    const u16* qbase = qh + ((size_t)head * SEQ + q0 + wave * 16) * HD;
    bf16x8 aq[4];
#pragma unroll
    for (int kk = 0; kk < 4; ++kk)
        aq[kk] = tob(ld8(qbase + l16 * HD + kk * 32 + quad * 8));

    f32x4 acco[8];
#pragma unroll
    for (int j = 0; j < 8; ++j) acco[j] = (f32x4){0.f, 0.f, 0.f, 0.f};
    float lsum = 0.f;

    const float sc = 0.08838834764831845f; // 1/sqrt(128)
    const u16* kbase = kh + (size_t)kvh * SEQ * HD;
    const u16* vbase = vt + (size_t)kvh * HD * SEQ;
    const int ntiles = qt + 1;
    u16* pw = &Ps[wave][0];
    const int qrow_g = q0 + wave * 16 + l16;

    const u16* kg0 = kbase + (size_t)tid * 8;
    const u16* vg0 = vbase + (size_t)(tid >> 3) * SEQ + (size_t)(tid & 7) * 8;
    int kst[4], vst[4];
#pragma unroll
    for (int r = 0; r < 4; ++r) {
        const int krow = r * 16 + (tid >> 4);
        kst[r] = krow * 128 + (((tid & 15) ^ (krow & 7)) << 3);
        const int vrow = r * 32 + (tid >> 3);
        vst[r] = vrow * 64 + (((tid & 7) ^ (vrow & 7)) << 3);
    }

    u16x8 kreg[4], vreg[4];
#pragma unroll
    for (int r = 0; r < 4; ++r) {
        kreg[r] = ld8(kg0 + (size_t)r * 2048);
        vreg[r] = ld8(vg0 + (size_t)r * 32 * SEQ);
    }
#pragma unroll
    for (int r = 0; r < 4; ++r) {
        *(u16x8*)(&Ks[0][0] + kst[r]) = kreg[r];
        *(u16x8*)(&Vts[0][0] + vst[r]) = vreg[r];
    }
    __syncthreads();

    for (int kt = 0; kt < ntiles; ++kt) {
        const int cur = kt & 1;
        const u16* ksc = &Ks[cur][0];
        const u16* vsc = &Vts[cur][0];

        if (kt + 1 < ntiles) {
            const size_t koff = (size_t)(kt + 1) * 64;
#pragma unroll
            for (int r = 0; r < 4; ++r) {
                kreg[r] = ld8(kg0 + koff * HD + (size_t)r * 2048);
                vreg[r] = ld8(vg0 + koff + (size_t)r * 32 * SEQ);
            }
        }

        f32x4 accs[4];
#pragma unroll
        for (int j = 0; j < 4; ++j) accs[j] = (f32x4){0.f, 0.f, 0.f, 0.f};
#pragma unroll
        for (int kk = 0; kk < 4; ++kk) {
#pragma unroll
            for (int j = 0; j < 4; ++j) {
                const int krow = j * 16 + l16;
                const bf16x8 bk = tob(ld8(ksc + krow * 128 + (((kk * 4 + quad) ^ (krow & 7)) << 3)));
                accs[j] = __builtin_amdgcn_mfma_f32_16x16x32_bf16(bk, aq[kk], accs[j], 0, 0, 0);
            }
        }

        const int k0 = kt * 64;
#pragma unroll
        for (int j = 0; j < 4; ++j) {
            u16x4 pk;
#pragma unroll
            for (int r = 0; r < 4; ++r) {
                const int kpos = k0 + j * 16 + quad * 4 + r;
                const float p = (kpos > qrow_g) ? 0.f : __expf(accs[j][r] * sc);
                lsum += p;
                pk[r] = f2b(p);
            }
            const int blk = (j * 2 + (quad >> 1)) ^ (l16 & 7);
            *(u16x4*)(pw + l16 * 64 + (blk << 3) + ((quad & 1) << 2)) = pk;
        }

        if (kt + 1 < ntiles) {
            u16* ksn = &Ks[1 - cur][0];
            u16* vsn = &Vts[1 - cur][0];
#pragma unroll
            for (int r = 0; r < 4; ++r) {
                *(u16x8*)(ksn + kst[r]) = kreg[r];
                *(u16x8*)(vsn + vst[r]) = vreg[r];
            }
        }

#pragma unroll
        for (int kk = 0; kk < 2; ++kk) {
            const bf16x8 ap = tob(ld8(pw + l16 * 64 + (((kk * 4 + quad) ^ (l16 & 7)) << 3)));
#pragma unroll
            for (int j = 0; j < 8; ++j) {
                const int vrow = j * 16 + l16;
                const bf16x8 bv = tob(ld8(vsc + vrow * 64 + (((kk * 4 + quad) ^ (vrow & 7)) << 3)));
                acco[j] = __builtin_amdgcn_mfma_f32_16x16x32_bf16(ap, bv, acco[j], 0, 0, 0);
            }
        }

        __syncthreads();
    }

    float v = lsum;
    v += __shfl_xor(v, 16);
    v += __shfl_xor(v, 32);
    f32x4 il;
#pragma unroll
    for (int r = 0; r < 4; ++r) il[r] = 1.0f / __shfl(v, quad * 4 + r);
    const int rowb = q0 + wave * 16 + quad * 4;
#pragma unroll
    for (int j = 0; j < 8; ++j) {
        const int col = head * HD + j * 16 + l16;
#pragma unroll
        for (int r = 0; r < 4; ++r)
            out[(size_t)(rowb + r) * 2048 + col] = f2b(acco[j][r] * il[r]);
    }
}

extern "C" void kernel_launch(void* const* d_in, const int* in_sizes, int n_in,
                              void* d_out, int out_size, void* d_ws, size_t ws_size,
                              hipStream_t stream) {
    const int*   positions = (const int*)d_in[0];
    const float* hidden   = (const float*)d_in[1];
    const float* lnw      = (const float*)d_in[2];
    const float* qkvw     = (const float*)d_in[3];
    const float* qnw      = (const float*)d_in[4];
    const float* knw      = (const float*)d_in[5];
    const float* ow       = (const float*)d_in[6];
    float* outp = (float*)d_out;

    char* ws = (char*)d_ws;
    const size_t MB = 1024ull * 1024ull;
    u16* normed = (u16*)(ws + 0 * MB);   // [S][2048] bf16 — dead after QKV gemm
    u16* qraw   = (u16*)(ws + 8 * MB);   // [16][S][128]
    u16* kraw   = (u16*)(ws + 16 * MB);  // [8][S][128]
    u16* vtr    = (u16*)(ws + 20 * MB);  // [8][128][S]
    u16* qkvwb  = (u16*)(ws + 24 * MB);  // [4096][2048] bf16 — dead after QKV gemm
    u16* owb    = (u16*)(ws + 0 * MB);   // [2048][2048] bf16, overwrites normed
    u16* attno  = (u16*)(ws + 24 * MB);  // [S][2048] bf16, overwrites qkvwb

    k_rmsnorm <<<SEQ, 256, 0, stream>>>(hidden, lnw, normed);
    k_conv    <<<4096, 256, 0, stream>>>(qkvw, qkvwb);
    k_gemm_qkv<<<dim3(16, 32), 256, 0, stream>>>(normed, qkvwb, qraw, kraw, vtr, HID);
    k_ropenorm<<<dim3(SEQ, 6), 256, 0, stream>>>(positions, qnw, knw, qraw, kraw);
    k_conv    <<<2048, 256, 0, stream>>>(ow, owb);
    k_attn    <<<dim3(32, 16), 256, 0, stream>>>(qraw, kraw, vtr, attno);
    k_gemm_of <<<dim3(16, 16), 256, 0, stream>>>(attno, owb, outp, HID, HID);
}

// Round 3
// 255.796 us; speedup vs baseline: 1.0429x; 1.0011x over previous
//
#include <hip/hip_runtime.h>
#include <hip/hip_bf16.h>
#include <stdint.h>

typedef unsigned short u16;
typedef __attribute__((ext_vector_type(4))) float f32x4;
typedef __attribute__((ext_vector_type(8))) __bf16 bf16x8;
typedef __attribute__((ext_vector_type(8))) unsigned short u16x8;
typedef __attribute__((ext_vector_type(4))) unsigned short u16x4;

#define SEQ 2048
#define HID 2048
#define HD  128

__device__ __forceinline__ float b2f(u16 v) {
    union { float f; unsigned u; } c; c.u = ((unsigned)v) << 16; return c.f;
}
__device__ __forceinline__ u16 f2b(float f) {
    union { float f; unsigned u; } c; c.f = f;
    unsigned r = c.u + 0x7fffu + ((c.u >> 16) & 1u);
    return (u16)(r >> 16);
}
__device__ __forceinline__ bf16x8 tob(u16x8 v) {
    union { u16x8 u; bf16x8 b; } c; c.u = v; return c.b;
}
__device__ __forceinline__ u16x8 ld8(const u16* p) { return *(const u16x8*)p; }

typedef const __attribute__((address_space(1))) unsigned int* gas_ptr;
typedef __attribute__((address_space(3))) unsigned int* las_ptr;
__device__ __forceinline__ void gld16(const void* g, void* l) {
    __builtin_amdgcn_global_load_lds((gas_ptr)g, (las_ptr)l, 16, 0, 0);
}

// ---------------- f32 -> bf16 weight conversion ----------------
__global__ __launch_bounds__(256) void k_conv(const float* __restrict__ src,
                                              u16* __restrict__ dst) {
    const size_t i = ((size_t)blockIdx.x * 256 + threadIdx.x) * 8;
    f32x4 a = *(const f32x4*)(src + i);
    f32x4 b = *(const f32x4*)(src + i + 4);
    u16x8 o;
#pragma unroll
    for (int e = 0; e < 4; ++e) { o[e] = f2b(a[e]); o[e + 4] = f2b(b[e]); }
    *(u16x8*)(dst + i) = o;
}

// ---------------- RMSNorm over HIDDEN (f32 in, bf16 out) ----------------
__global__ __launch_bounds__(256) void k_rmsnorm(const float* __restrict__ x,
                                                 const float* __restrict__ w,
                                                 u16* __restrict__ o) {
    const int row = blockIdx.x, t = threadIdx.x;
    const float* xr = x + (size_t)row * HID + t * 8;
    f32x4 xa = *(const f32x4*)xr;
    f32x4 xb = *(const f32x4*)(xr + 4);
    float xf[8]; float ss = 0.f;
#pragma unroll
    for (int e = 0; e < 4; ++e) { xf[e] = xa[e]; xf[e + 4] = xb[e]; }
#pragma unroll
    for (int e = 0; e < 8; ++e) ss += xf[e] * xf[e];
#pragma unroll
    for (int m = 32; m; m >>= 1) ss += __shfl_xor(ss, m);
    __shared__ float red[4];
    if ((t & 63) == 0) red[t >> 6] = ss;
    __syncthreads();
    ss = red[0] + red[1] + red[2] + red[3];
    const float sc = rsqrtf(ss * (1.0f / HID) + 1e-6f);
    f32x4 wa = *(const f32x4*)(w + t * 8);
    f32x4 wb = *(const f32x4*)(w + t * 8 + 4);
    u16x8 ov;
#pragma unroll
    for (int e = 0; e < 4; ++e) {
        ov[e] = f2b(xf[e] * sc * wa[e]);
        ov[e + 4] = f2b(xf[e + 4] * sc * wb[e]);
    }
    *(u16x8*)(o + (size_t)row * HID + t * 8) = ov;
}

// Staging: 8 gld16 per wave per tile. LDS dest linear; chunk permutation on the
// GLOBAL source address (rule #21); reads apply the same XOR.
#define STAGE_G(buf, k0)                                                      \
    do {                                                                      \
        char* a0 = (char*)&As[buf][0][0] + wave * 1024;                       \
        char* a1 = (char*)&As[buf][1][0] + wave * 1024;                       \
        char* b0 = (char*)&Bs[buf][0][0] + wave * 1024;                       \
        char* b1 = (char*)&Bs[buf][1][0] + wave * 1024;                       \
        gld16(ga + (k0), a0);                                                 \
        gld16(ga + (k0) + rowskip, a0 + 4096);                                \
        gld16(ga + (k0) + 32, a1);                                            \
        gld16(ga + (k0) + 32 + rowskip, a1 + 4096);                           \
        gld16(gb + (k0), b0);                                                 \
        gld16(gb + (k0) + rowskip, b0 + 4096);                                \
        gld16(gb + (k0) + 32, b1);                                            \
        gld16(gb + (k0) + 32 + rowskip, b1 + 4096);                           \
    } while (0)

// ------- QKV GEMM: dbuf LDS, counted vmcnt(8), swizzled reads, scatter epilogue -------
__global__ __launch_bounds__(256) void k_gemm_qkv(const u16* __restrict__ A,
                                                  const u16* __restrict__ B,
                                                  u16* __restrict__ qraw,
                                                  u16* __restrict__ kraw,
                                                  u16* __restrict__ vtr,
                                                  int K) {
    __shared__ u16 As[2][2][128 * 32];
    __shared__ u16 Bs[2][2][128 * 32];
    const int tid = threadIdx.x;
    const int wave = tid >> 6, lane = tid & 63, quad = lane >> 4, l16 = lane & 15;
    const int wm = wave >> 1, wn = wave & 1;
    const int sw = (l16 >> 1) & 3;
    const int m0 = blockIdx.x * 128, n0 = blockIdx.y * 128;
    f32x4 acc[4][4];
#pragma unroll
    for (int i = 0; i < 4; ++i)
#pragma unroll
        for (int j = 0; j < 4; ++j) acc[i][j] = (f32x4){0.f, 0.f, 0.f, 0.f};

    const int gchunk = (tid & 3) ^ ((tid >> 3) & 3);
    const u16* ga = A + (size_t)(m0 + (tid >> 2)) * K + gchunk * 8;
    const u16* gb = B + (size_t)(n0 + (tid >> 2)) * K + gchunk * 8;
    const size_t rowskip = (size_t)64 * K;

    STAGE_G(0, 0);
    const int nk = K >> 6;
    for (int t = 0; t < nk; ++t) {
        const int cur = t & 1;
        if (t + 1 < nk) {
            STAGE_G(cur ^ 1, (t + 1) * 64);
            asm volatile("s_waitcnt vmcnt(8)" ::: "memory");
        } else {
            asm volatile("s_waitcnt vmcnt(0)" ::: "memory");
        }
        __builtin_amdgcn_s_barrier();
        asm volatile("" ::: "memory");
#pragma unroll
        for (int h = 0; h < 2; ++h) {
            const u16* as = &As[cur][h][0];
            const u16* bs = &Bs[cur][h][0];
            bf16x8 af[4], bfr[4];
#pragma unroll
            for (int i = 0; i < 4; ++i)
                af[i] = tob(ld8(as + (wm * 64 + i * 16 + l16) * 32 + ((quad ^ sw) << 3)));
#pragma unroll
            for (int j = 0; j < 4; ++j)
                bfr[j] = tob(ld8(bs + (wn * 64 + j * 16 + l16) * 32 + ((quad ^ sw) << 3)));
#pragma unroll
            for (int i = 0; i < 4; ++i)
#pragma unroll
                for (int j = 0; j < 4; ++j)
                    acc[i][j] = __builtin_amdgcn_mfma_f32_16x16x32_bf16(af[i], bfr[j], acc[i][j], 0, 0, 0);
        }
        asm volatile("" ::: "memory");
        __builtin_amdgcn_s_barrier();
    }
#pragma unroll
    for (int i = 0; i < 4; ++i) {
        const int row = m0 + wm * 64 + i * 16 + quad * 4;
#pragma unroll
        for (int j = 0; j < 4; ++j) {
            const int col = n0 + wn * 64 + j * 16 + l16;
#pragma unroll
            for (int r = 0; r < 4; ++r) {
                const u16 val = f2b(acc[i][j][r]);
                const int s = row + r;
                if (col < 2048) {
                    const int head = col >> 7, d = col & 127;
                    qraw[((size_t)head * SEQ + s) * HD + d] = val;
                } else if (col < 3072) {
                    const int c = col - 2048, kv = c >> 7, d = c & 127;
                    kraw[((size_t)kv * SEQ + s) * HD + d] = val;
                } else {
                    const int c = col - 3072, kv = c >> 7, d = c & 127;
                    vtr[(size_t)kv * HD * SEQ + (size_t)d * SEQ + s] = val;
                }
            }
        }
    }
}

// ------- O-projection GEMM: same dbuf + counted vmcnt + swizzle, f32 epilogue -------
__global__ __launch_bounds__(256) void k_gemm_of(const u16* __restrict__ A,
                                                 const u16* __restrict__ B,
                                                 float* __restrict__ C,
                                                 int N, int K) {
    __shared__ u16 As[2][2][128 * 32];
    __shared__ u16 Bs[2][2][128 * 32];
    const int tid = threadIdx.x;
    const int wave = tid >> 6, lane = tid & 63, quad = lane >> 4, l16 = lane & 15;
    const int wm = wave >> 1, wn = wave & 1;
    const int sw = (l16 >> 1) & 3;
    const int m0 = blockIdx.x * 128, n0 = blockIdx.y * 128;
    f32x4 acc[4][4];
#pragma unroll
    for (int i = 0; i < 4; ++i)
#pragma unroll
        for (int j = 0; j < 4; ++j) acc[i][j] = (f32x4){0.f, 0.f, 0.f, 0.f};

    const int gchunk = (tid & 3) ^ ((tid >> 3) & 3);
    const u16* ga = A + (size_t)(m0 + (tid >> 2)) * K + gchunk * 8;
    const u16* gb = B + (size_t)(n0 + (tid >> 2)) * K + gchunk * 8;
    const size_t rowskip = (size_t)64 * K;

    STAGE_G(0, 0);
    const int nk = K >> 6;
    for (int t = 0; t < nk; ++t) {
        const int cur = t & 1;
        if (t + 1 < nk) {
            STAGE_G(cur ^ 1, (t + 1) * 64);
            asm volatile("s_waitcnt vmcnt(8)" ::: "memory");
        } else {
            asm volatile("s_waitcnt vmcnt(0)" ::: "memory");
        }
        __builtin_amdgcn_s_barrier();
        asm volatile("" ::: "memory");
#pragma unroll
        for (int h = 0; h < 2; ++h) {
            const u16* as = &As[cur][h][0];
            const u16* bs = &Bs[cur][h][0];
            bf16x8 af[4], bfr[4];
#pragma unroll
            for (int i = 0; i < 4; ++i)
                af[i] = tob(ld8(as + (wm * 64 + i * 16 + l16) * 32 + ((quad ^ sw) << 3)));
#pragma unroll
            for (int j = 0; j < 4; ++j)
                bfr[j] = tob(ld8(bs + (wn * 64 + j * 16 + l16) * 32 + ((quad ^ sw) << 3)));
#pragma unroll
            for (int i = 0; i < 4; ++i)
#pragma unroll
                for (int j = 0; j < 4; ++j)
                    acc[i][j] = __builtin_amdgcn_mfma_f32_16x16x32_bf16(af[i], bfr[j], acc[i][j], 0, 0, 0);
        }
        asm volatile("" ::: "memory");
        __builtin_amdgcn_s_barrier();
    }
#pragma unroll
    for (int i = 0; i < 4; ++i) {
        const int row = m0 + wm * 64 + i * 16 + quad * 4;
#pragma unroll
        for (int j = 0; j < 4; ++j) {
            const int col = n0 + wn * 64 + j * 16 + l16;
#pragma unroll
            for (int r = 0; r < 4; ++r)
                C[(size_t)(row + r) * N + col] = acc[i][j][r];
        }
    }
}

// ---------------- in-place RoPE + per-head RMSNorm ----------------
__global__ __launch_bounds__(256) void k_ropenorm(const int* __restrict__ pos,
                                                  const float* __restrict__ qw,
                                                  const float* __restrict__ kw,
                                                  u16* __restrict__ qraw,
                                                  u16* __restrict__ kraw) {
    const int s = blockIdx.x;
    const int h = blockIdx.y * 4 + (threadIdx.x >> 6);
    const int d = threadIdx.x & 63;
    const bool isq = h < 16;
    u16* row = isq ? (qraw + ((size_t)h * SEQ + s) * HD)
                   : (kraw + ((size_t)(h - 16) * SEQ + s) * HD);
    const float x1 = b2f(row[d]), x2 = b2f(row[d + 64]);
    const float p = (float)pos[s];
    const float inv = exp2f(-(float)d * (2.0f / 128.0f) * 13.287712379549449f);
    const float fr = p * inv;
    const float c = cosf(fr), sn = sinf(fr);
    const float o1 = x1 * c - x2 * sn;
    const float o2 = x2 * c + x1 * sn;
    float ss = o1 * o1 + o2 * o2;
#pragma unroll
    for (int m = 32; m; m >>= 1) ss += __shfl_xor(ss, m);
    const float sc = rsqrtf(ss * (1.0f / HD) + 1e-6f);
    const float* w = isq ? qw : kw;
    row[d] = f2b(o1 * sc * w[d]);
    row[d + 64] = f2b(o2 * sc * w[d + 64]);
}

// ---------------- causal flash attention, 8-wave split-K ----------------
// M=0 softmax (P = exp(s*sc)) makes the k-dimension a pure sum -> two 4-wave
// groups process even/odd k-tiles into private single-buffered K/V LDS, then
// merge acco/lsum through LDS once at the end. 80 KiB LDS -> 2 blocks/CU
// -> 16 waves/CU (was 8): doubles latency overlap per SIMD.
__global__ __launch_bounds__(512, 4) void k_attn(const u16* __restrict__ qh,
                                                 const u16* __restrict__ kh,
                                                 const u16* __restrict__ vt,
                                                 u16* __restrict__ out) {
    const int tid = threadIdx.x;
    const int wave = tid >> 6, lane = tid & 63, quad = lane >> 4, l16 = lane & 15;
    const int gid = wave >> 2;        // k-split group
    const int wv = wave & 3;          // 16-row slice within group
    const int gtid = tid & 255;       // thread id within group
    const int head = blockIdx.y;
    const int bx = blockIdx.x;
    const int f = (bx & 1) ? 31 - (bx >> 1) : (bx >> 1);
    const int qt = (head < 8) ? f : 31 - f;
    const int kvh = head >> 1;
    const int q0 = qt * 64;

    __shared__ u16 Ks[2][64 * 128];    // [group][kpos][d]  (single-buffered per group)
    __shared__ u16 Vts[2][128 * 64];   // [group][d][kpos]
    __shared__ u16 Ps[8][16 * 64];     // per-wave P scratch

    const u16* qbase = qh + ((size_t)head * SEQ + q0 + wv * 16) * HD;
    bf16x8 aq[4];
#pragma unroll
    for (int kk = 0; kk < 4; ++kk)
        aq[kk] = tob(ld8(qbase + l16 * HD + kk * 32 + quad * 8));

    f32x4 acco[8];
#pragma unroll
    for (int j = 0; j < 8; ++j) acco[j] = (f32x4){0.f, 0.f, 0.f, 0.f};
    float lsum = 0.f;

    const float sc = 0.08838834764831845f; // 1/sqrt(128)
    const u16* kbase = kh + (size_t)kvh * SEQ * HD;
    const u16* vbase = vt + (size_t)kvh * HD * SEQ;
    const int ntiles = qt + 1;
    const int niter = (ntiles + 1) >> 1;
    u16* pw = &Ps[wave][0];
    const int qrow_g = q0 + wv * 16 + l16;

    const u16* kg0 = kbase + (size_t)gtid * 8;
    const u16* vg0 = vbase + (size_t)(gtid >> 3) * SEQ + (size_t)(gtid & 7) * 8;
    int kst[4], vst[4];
#pragma unroll
    for (int r = 0; r < 4; ++r) {
        const int krow = r * 16 + (gtid >> 4);
        kst[r] = krow * 128 + (((gtid & 15) ^ (krow & 7)) << 3);
        const int vrow = r * 32 + (gtid >> 3);
        vst[r] = vrow * 64 + (((gtid & 7) ^ (vrow & 7)) << 3);
    }
    u16* ksg = &Ks[gid][0];
    u16* vsg = &Vts[gid][0];

    // prologue: each group stages tile kt=gid (addresses valid even if unused)
    u16x8 kreg[4], vreg[4];
    {
        const size_t koff = (size_t)gid * 64;
#pragma unroll
        for (int r = 0; r < 4; ++r) {
            kreg[r] = ld8(kg0 + koff * HD + (size_t)r * 2048);
            vreg[r] = ld8(vg0 + koff + (size_t)r * 32 * SEQ);
        }
#pragma unroll
        for (int r = 0; r < 4; ++r) {
            *(u16x8*)(ksg + kst[r]) = kreg[r];
            *(u16x8*)(vsg + vst[r]) = vreg[r];
        }
    }
    __syncthreads();

    for (int i = 0; i < niter; ++i) {
        const int kt = 2 * i + gid;
        const bool active = kt < ntiles;
        const bool havenext = (kt + 2) < ntiles;

        if (havenext) {
            const size_t koff = (size_t)(kt + 2) * 64;
#pragma unroll
            for (int r = 0; r < 4; ++r) {
                kreg[r] = ld8(kg0 + koff * HD + (size_t)r * 2048);
                vreg[r] = ld8(vg0 + koff + (size_t)r * 32 * SEQ);
            }
        }

        if (active) {
            // S^T = K Q^T
            f32x4 accs[4];
#pragma unroll
            for (int j = 0; j < 4; ++j) accs[j] = (f32x4){0.f, 0.f, 0.f, 0.f};
#pragma unroll
            for (int kk = 0; kk < 4; ++kk) {
#pragma unroll
                for (int j = 0; j < 4; ++j) {
                    const int krow = j * 16 + l16;
                    const bf16x8 bk = tob(ld8(ksg + krow * 128 + (((kk * 4 + quad) ^ (krow & 7)) << 3)));
                    accs[j] = __builtin_amdgcn_mfma_f32_16x16x32_bf16(bk, aq[kk], accs[j], 0, 0, 0);
                }
            }

            // P = exp(s*sc) (M=0), causal mask -> 0
            const int k0 = kt * 64;
#pragma unroll
            for (int j = 0; j < 4; ++j) {
                u16x4 pk;
#pragma unroll
                for (int r = 0; r < 4; ++r) {
                    const int kpos = k0 + j * 16 + quad * 4 + r;
                    const float p = (kpos > qrow_g) ? 0.f : __expf(accs[j][r] * sc);
                    lsum += p;
                    pk[r] = f2b(p);
                }
                const int blk = (j * 2 + (quad >> 1)) ^ (l16 & 7);
                *(u16x4*)(pw + l16 * 64 + (blk << 3) + ((quad & 1) << 2)) = pk;
            }

            // O += P V (Ps wave-private, DS in-order -> no barrier)
#pragma unroll
            for (int kk = 0; kk < 2; ++kk) {
                const bf16x8 ap = tob(ld8(pw + l16 * 64 + (((kk * 4 + quad) ^ (l16 & 7)) << 3)));
#pragma unroll
                for (int j = 0; j < 8; ++j) {
                    const int vrow = j * 16 + l16;
                    const bf16x8 bv = tob(ld8(vsg + vrow * 64 + (((kk * 4 + quad) ^ (vrow & 7)) << 3)));
                    acco[j] = __builtin_amdgcn_mfma_f32_16x16x32_bf16(ap, bv, acco[j], 0, 0, 0);
                }
            }
        }

        __syncthreads(); // all reads of this iter done
        if (havenext) {
#pragma unroll
            for (int r = 0; r < 4; ++r) {
                *(u16x8*)(ksg + kst[r]) = kreg[r];
                *(u16x8*)(vsg + vst[r]) = vreg[r];
            }
        }
        __syncthreads(); // stores visible before next-iter reads
    }

    // merge group 1 into group 0 through LDS (Ks/Vts are dead now)
    float* mo = (float*)&Ks[0][0];   // 32 KB: 4 waves x 64 lanes x 32 f32
    float* ml = (float*)&Vts[0][0];  // 1 KB
    if (gid == 1) {
#pragma unroll
        for (int j = 0; j < 8; ++j)
            *(f32x4*)(mo + (size_t)wv * 2048 + lane * 32 + ((j ^ (lane & 7)) << 2)) = acco[j];
        ml[wv * 64 + lane] = lsum;
    }
    __syncthreads();
    if (gid == 0) {
#pragma unroll
        for (int j = 0; j < 8; ++j) {
            const f32x4 p = *(const f32x4*)(mo + (size_t)wv * 2048 + lane * 32 + ((j ^ (lane & 7)) << 2));
            acco[j] += p;
        }
        lsum += ml[wv * 64 + lane];

        float v = lsum;
        v += __shfl_xor(v, 16);
        v += __shfl_xor(v, 32);
        f32x4 il;
#pragma unroll
        for (int r = 0; r < 4; ++r) il[r] = 1.0f / __shfl(v, quad * 4 + r);
        const int rowb = q0 + wv * 16 + quad * 4;
#pragma unroll
        for (int j = 0; j < 8; ++j) {
            const int col = head * HD + j * 16 + l16;
#pragma unroll
            for (int r = 0; r < 4; ++r)
                out[(size_t)(rowb + r) * 2048 + col] = f2b(acco[j][r] * il[r]);
        }
    }
}

extern "C" void kernel_launch(void* const* d_in, const int* in_sizes, int n_in,
                              void* d_out, int out_size, void* d_ws, size_t ws_size,
                              hipStream_t stream) {
    const int*   positions = (const int*)d_in[0];
    const float* hidden   = (const float*)d_in[1];
    const float* lnw      = (const float*)d_in[2];
    const float* qkvw     = (const float*)d_in[3];
    const float* qnw      = (const float*)d_in[4];
    const float* knw      = (const float*)d_in[5];
    const float* ow       = (const float*)d_in[6];
    float* outp = (float*)d_out;

    char* ws = (char*)d_ws;
    const size_t MB = 1024ull * 1024ull;
    u16* normed = (u16*)(ws + 0 * MB);   // [S][2048] bf16 — dead after QKV gemm
    u16* qraw   = (u16*)(ws + 8 * MB);   // [16][S][128]
    u16* kraw   = (u16*)(ws + 16 * MB);  // [8][S][128]
    u16* vtr    = (u16*)(ws + 20 * MB);  // [8][128][S]
    u16* qkvwb  = (u16*)(ws + 24 * MB);  // [4096][2048] bf16 — dead after QKV gemm
    u16* owb    = (u16*)(ws + 0 * MB);   // [2048][2048] bf16, overwrites normed
    u16* attno  = (u16*)(ws + 24 * MB);  // [S][2048] bf16, overwrites qkvwb

    k_rmsnorm <<<SEQ, 256, 0, stream>>>(hidden, lnw, normed);
    k_conv    <<<4096, 256, 0, stream>>>(qkvw, qkvwb);
    k_gemm_qkv<<<dim3(16, 32), 256, 0, stream>>>(normed, qkvwb, qraw, kraw, vtr, HID);
    k_ropenorm<<<dim3(SEQ, 6), 256, 0, stream>>>(positions, qnw, knw, qraw, kraw);
    k_conv    <<<2048, 256, 0, stream>>>(ow, owb);
    k_attn    <<<dim3(32, 16), 512, 0, stream>>>(qraw, kraw, vtr, attno);
    k_gemm_of <<<dim3(16, 16), 256, 0, stream>>>(attno, owb, outp, HID, HID);
}